// Round 7
// baseline (184.324 us; speedup 1.0000x reference)
//
#include <hip/hip_runtime.h>
#include <stdint.h>

// Problem: out[m][n] = sum_k x[m][k] * w[n][k] + bias[n]
//   M=256, N=16384, K=4096, w = dequant(2-bit, group=16 along k)
// Harness dtype universe {bf16,int32,float32}: fp16 weight_norm arrives as f32.
//
// History:
//  R3: BK=64 LDS skeleton -> 92 us, nothing saturated.
//  R4/R5: VGPR prefetch across barriers -> SPILLS (WRITE_SIZE 190-287 MB). Never again.
//  R6: KSPLIT=2 -> 86 us. Diagnosis: per-iter chain ~1600cyc dominated by in-chain
//      q2 HBM latency (~900cyc); pipes fully serialized (dur == sum of pipes).
//  R7: q2/nrm one-iter-ahead via global_load_lds dbuf (no VGPR state), B dequant
//      direct to MFMA regs (no B LDS), A via global_load_lds, raw s_barrier with
//      explicit s_waitcnt vmcnt(2) so the q2 prefetch is never drained early.
#define M_DIM 256
#define N_DIM 16384
#define K_DIM 4096
#define BM 128
#define BN 64
#define BK 64
#define KSPLIT 2
#define KSLICE (K_DIM / KSPLIT)   // 2048

typedef __bf16 bf16x8 __attribute__((ext_vector_type(8)));
typedef float  f32x4  __attribute__((ext_vector_type(4)));

// fp32 -> bf16 bits, round-nearest-even (finite inputs)
__device__ __forceinline__ uint32_t f2bf(float f) {
  uint32_t u = __float_as_uint(f);
  return (u + 0x7fffu + ((u >> 16) & 1u)) >> 16;
}

// s_waitcnt with vmcnt=N only (lgkm=15, exp=7 -> no wait). gfx9 encoding:
// vm[3:0]|exp[6:4]|lgkm[11:8]|vm[5:4]@[15:14]
#define WAITVM(N) __builtin_amdgcn_s_waitcnt(0x0F70 | ((N) & 0xF) | (((N) >> 4) << 14))

// async global->LDS DMA, 16B/lane. LDS dest = uniform base + lane*16.
__device__ __forceinline__ void dma16(const void* g, void* l) {
  __builtin_amdgcn_global_load_lds(
      (const __attribute__((address_space(1))) uint32_t*)g,
      (__attribute__((address_space(3))) uint32_t*)l, 16, 0, 0);
}

// ---------------------------------------------------------------------------
// Kernel 1: x fp32 [256][4096] -> bf16 fragment-chunk order in workspace.
// Chunk = (m-block of 16 rows) x (k-chunk of 32): 64 slots x 16B.
// Slot L holds row (L&15), k = (L>>4)*8 .. +7  (MFMA 16x16x32 A-frag order).
// ws uint4 index = (mb_glob*128 + kch)*64 + L.
// ---------------------------------------------------------------------------
__global__ __launch_bounds__(256) void cvt_x_kernel(const float* __restrict__ x,
                                                    uint4* __restrict__ ws) {
  int T = blockIdx.x * 256 + threadIdx.x;       // 0..131071
  int mb_glob = T >> 13;                        // 16 m-blocks
  int r       = T & 8191;
  int kch     = r >> 6;                         // 128 k-chunks
  int L       = r & 63;
  int row = mb_glob * 16 + (L & 15);
  int k   = kch * 32 + (L >> 4) * 8;
  const float* p = x + (size_t)row * K_DIM + k;
  float4 a = *(const float4*)p;
  float4 b = *(const float4*)(p + 4);
  uint4 o;
  o.x = f2bf(a.x) | (f2bf(a.y) << 16);
  o.y = f2bf(a.z) | (f2bf(a.w) << 16);
  o.z = f2bf(b.x) | (f2bf(b.y) << 16);
  o.w = f2bf(b.z) | (f2bf(b.w) << 16);
  ws[T] = o;
}

// ---------------------------------------------------------------------------
// Kernel 2: 2-bit dequant + bf16 MFMA GEMM, DMA-pipelined.
// Grid (N/64, M/128, 2), 256 thr (2x2 waves, wave tile 64x32, 16x16x32 MFMA).
// Per iter: [waitvm(0); barrier] -> A-DMA(cur) + Q-DMA(next) -> dequant B frags
// from LDS q2 (covers A flight) -> [waitvm(2); barrier] -> ds_read A + MFMA.
// vmcnt(2) releases A's 4 DMAs while the 2 next-iter Q-DMAs keep flying.
// ---------------------------------------------------------------------------
__global__ __launch_bounds__(256, 4) void gemm2bit_kernel(
    const uint4*    __restrict__ aws,  // A fragment chunks (see cvt)
    const uint32_t* __restrict__ q2,   // [G][4] packed 2-bit (crumbs in bytes)
    const float*    __restrict__ nrm,  // [G] group norms (fp32)
    const float*    __restrict__ bias, // [N]
    float*          __restrict__ out)  // [256][16384] fp32, pre-zeroed
{
  __shared__ uint4 Ab[1024];     // 16 KiB: A chunks (ts*8+mb) x 64 slots
  __shared__ uint4 Qb[2][256];   // 2x4 KiB: q2 tile, slot = kg*64 + row
  __shared__ float Nb[2][256];   // 2x1 KiB: norms, idx = row*4 + kg

  const int tid  = threadIdx.x;
  const int l    = tid & 63;
  const int w    = tid >> 6;
  const int wm   = w >> 1;
  const int wn   = w & 1;
  const int lo4  = l & 15;
  const int qd   = l >> 4;

  const int n0    = blockIdx.x * BN;
  const int m0    = blockIdx.y * BM;
  const int kbase = blockIdx.z * KSLICE;
  const int kend  = kbase + KSLICE;

  f32x4 acc[4][2];
#pragma unroll
  for (int s = 0; s < 4; ++s)
#pragma unroll
    for (int u = 0; u < 2; ++u)
      acc[s][u] = (f32x4){0.f, 0.f, 0.f, 0.f};

  // B-frag role of lane l (16x16x32 B operand, proven mapping):
  // row = lo4 (+ u*16 + wn*32), kg = ts*2 + (l>>5), half = (l>>4)&1.
  const int kgl  = l >> 5;
  const int half = (l >> 4) & 1;

  // ---- prologue: prefetch Q for first iter into buf 0 ----
  // q2: wave w covers kg=w, lane covers row (uncoalesced 4KiB stride; the 4
  // waves' kg 0..3 share each row's 64B line). nrm: 16B = kg 0..3 of row=lane;
  // all 4 waves write identical data (benign race).
  dma16(q2 + ((size_t)(n0 + l) * 256 + (kbase >> 4) + w) * 4, &Qb[0][w * 64]);
  dma16(nrm + (size_t)(n0 + l) * 256 + (kbase >> 4), &Nb[0][0]);

#define BODY(KC, CUR, NXT)                                                     \
  {                                                                            \
    WAITVM(0);                          /* drain own Q-DMA into CUR */         \
    __builtin_amdgcn_s_barrier();       /* Qb[CUR] ready; Ab free */           \
    /* A-DMA (this iter), issued FIRST so vmcnt(2) releases them */            \
    _Pragma("unroll") for (int j = 0; j < 4; ++j) {                            \
      int c = j * 4 + w;                                                       \
      dma16(aws + ((size_t)(blockIdx.y * 8 + (c & 7)) * 128 + ((KC) >> 5) +    \
                   (c >> 3)) * 64 + l,                                         \
            &Ab[c * 64]);                                                      \
    }                                                                          \
    /* Q-DMA for next iter (clamped on last: junk prefetch, never read) */     \
    int kn = (KC) + BK; if (kn >= kend) kn = kbase;                            \
    dma16(q2 + ((size_t)(n0 + l) * 256 + (kn >> 4) + w) * 4, &Qb[NXT][w * 64]);\
    dma16(nrm + (size_t)(n0 + l) * 256 + (kn >> 4), &Nb[NXT][0]);              \
    /* dequant 4 B-frags from Qb[CUR] (VALU+DS; overlaps A-DMA flight) */      \
    bf16x8 bfr[2][2];                                                          \
    _Pragma("unroll") for (int ts = 0; ts < 2; ++ts)                           \
    _Pragma("unroll") for (int u = 0; u < 2; ++u) {                            \
      int row = wn * 32 + u * 16 + lo4;                                        \
      int kg  = ts * 2 + kgl;                                                  \
      uint2 qh = *(const uint2*)((const char*)&Qb[CUR][kg * 64 + row] +        \
                                 half * 8);                                    \
      float nv = Nb[CUR][row * 4 + kg];                                        \
      uint32_t u3  = f2bf(nv);                                                 \
      uint32_t u1  = f2bf(nv * 0.33333334f);                                   \
      uint32_t T01 = (u3 | (u1 << 16)) ^ 0x80008000u;  /* [-n, -n/3] */        \
      uint32_t T23 = u1 | (u3 << 16);                  /* [+n/3, +n] */        \
      union { uint32_t r[4]; bf16x8 v; } fr;                                   \
      _Pragma("unroll") for (int p = 0; p < 2; ++p) {                          \
        uint32_t qq  = p ? qh.y : qh.x;                                        \
        uint32_t v01 = (qq & 3u) | ((qq & 0x0Cu) << 14);                       \
        uint32_t v23 = ((qq >> 4) & 3u) | ((qq & 0xC0u) << 10);                \
        fr.r[p * 2]     = __builtin_amdgcn_perm(T23, T01,                      \
                              v01 * 0x0202u + 0x01000100u);                    \
        fr.r[p * 2 + 1] = __builtin_amdgcn_perm(T23, T01,                      \
                              v23 * 0x0202u + 0x01000100u);                    \
      }                                                                        \
      bfr[ts][u] = fr.v;                                                       \
    }                                                                          \
    WAITVM(2);                          /* A done; 2 Q-DMAs keep flying */     \
    __builtin_amdgcn_s_barrier();       /* Ab ready for all waves */           \
    /* compute: ds_read A frags + 16 MFMAs */                                  \
    _Pragma("unroll") for (int ts = 0; ts < 2; ++ts) {                         \
      bf16x8 af[4];                                                            \
      _Pragma("unroll") for (int s = 0; s < 4; ++s)                            \
        af[s] = *(const bf16x8*)&Ab[(ts * 8 + wm * 4 + s) * 64 + l];           \
      _Pragma("unroll") for (int s = 0; s < 4; ++s)                            \
      _Pragma("unroll") for (int u = 0; u < 2; ++u)                            \
        acc[s][u] = __builtin_amdgcn_mfma_f32_16x16x32_bf16(                   \
            af[s], bfr[ts][u], acc[s][u], 0, 0, 0);                            \
    }                                                                          \
  }

  for (int kc = kbase; kc < kend; kc += 2 * BK) {
    BODY(kc, 0, 1)
    BODY(kc + BK, 1, 0)
  }
#undef BODY

  WAITVM(0);  // retire the clamped tail prefetch before epilogue

  // ---- epilogue: C/D layout col=lane&15 (n), row=(lane>>4)*4+reg (m) ----
  float bv[2];
#pragma unroll
  for (int u = 0; u < 2; ++u)
    bv[u] = (blockIdx.z == 0) ? bias[n0 + wn * 32 + u * 16 + lo4] : 0.0f;

#pragma unroll
  for (int s = 0; s < 4; ++s) {
    int mrow = m0 + wm * 64 + s * 16 + qd * 4;
#pragma unroll
    for (int u = 0; u < 2; ++u) {
      int ncol = n0 + wn * 32 + u * 16 + lo4;
      float* p = out + (size_t)mrow * N_DIM + ncol;
#pragma unroll
      for (int r = 0; r < 4; ++r)
        atomicAdd(p + (size_t)r * N_DIM, acc[s][u][r] + bv[u]);
    }
  }
}

// ---------------------------------------------------------------------------
extern "C" void kernel_launch(void* const* d_in, const int* in_sizes, int n_in,
                              void* d_out, int out_size, void* d_ws, size_t ws_size,
                              hipStream_t stream) {
  const float*    x    = (const float*)d_in[0];
  const uint32_t* q2   = (const uint32_t*)d_in[1];
  const float*    nm   = (const float*)d_in[2];
  const float*    bias = (const float*)d_in[3];
  float*          out  = (float*)d_out;
  uint4*          aws  = (uint4*)d_ws;   // 2 MiB: x as bf16 fragment chunks

  // zero output: k-split halves accumulate via atomicAdd
  hipMemsetAsync(d_out, 0, (size_t)out_size * sizeof(float), stream);

  cvt_x_kernel<<<512, 256, 0, stream>>>(x, aws);

  dim3 grid(N_DIM / BN, M_DIM / BM, KSPLIT);
  gemm2bit_kernel<<<grid, 256, 0, stream>>>(aws, q2, nm, bias, out);
}